// Round 2
// baseline (559.627 us; speedup 1.0000x reference)
//
#include <hip/hip_runtime.h>

// detection_head: six 1x1 convs over [4,252,252,384] fp32 -> 52 channels.
// Single fused kernel: per-pixel GEMM M=254016, K=384, N=52 (padded 64) via
// mfma_f32_16x16x32_bf16. Weights (80 KB fp32) are converted to a bf16 LDS
// image in each block's prologue (L2-resident after first block) -- no prep
// kernel, no workspace dependency. Each block computes 3 64-pixel tiles so
// one LDS weight staging feeds 3x the MFMAs.
// Memory-bound: 390 MB x-read + 53 MB out-write -> ~69 us roofline.

#define HH 252
#define WW 252
#define BB 4
#define CIN 384
#define PIX (BB*HH*WW)            // 254016
#define NPAD 64
#define KPAD 392                  // 384 + 8 bf16 pad -> row stride 784 B
#define WIMG_USHORTS (NPAD*KPAD)  // 25088
#define WIMG_BYTES (WIMG_USHORTS*2)       // 50176
#define LDS_BYTES (WIMG_BYTES + NPAD*4)   // 50432
#define TILES_PB 3
#define PIX_PB (TILES_PB*64)      // 192 pixels/block
#define NBLOCKS (PIX / PIX_PB)    // 1323 (exact: 254016 = 1323*192)

typedef __attribute__((ext_vector_type(8))) short short8;
typedef __attribute__((ext_vector_type(4))) float f32x4;

__device__ __forceinline__ unsigned bfpk(float a, float b) {
  // two RNE bf16 packed into one u32 (low = a, high = b)
  unsigned ua = __float_as_uint(a), ub = __float_as_uint(b);
  ua = (ua + 0x7FFFu + ((ua >> 16) & 1u)) >> 16;
  ub = (ub + 0x7FFFu + ((ub >> 16) & 1u)) >> 16;
  return ua | (ub << 16);
}

// Block = 256 threads = 4 waves; each wave owns M=16 rows of 3 tiles (N=64).
__global__ __launch_bounds__(256, 3) void head_kernel(
    const float* __restrict__ x,
    const float* __restrict__ occ_w, const float* __restrict__ occ_b,
    const float* __restrict__ loc_w, const float* __restrict__ loc_b,
    const float* __restrict__ ang_w, const float* __restrict__ ang_b,
    const float* __restrict__ siz_w, const float* __restrict__ siz_b,
    const float* __restrict__ hea_w, const float* __restrict__ hea_b,
    const float* __restrict__ clf_w, const float* __restrict__ clf_b,
    float* __restrict__ out) {
  __shared__ __align__(16) unsigned char lds_raw[LDS_BYTES];
  unsigned short* Wl = (unsigned short*)lds_raw;
  float* biasl = (float*)(lds_raw + WIMG_BYTES);

  // ---- Prologue: pack 6 weight mats into bf16 [64][KPAD] + 64 f32 biases.
  // One chunk = 8 ushorts (16 B ds_write). 64 rows x 49 chunks = 3136 chunks.
  for (int c = threadIdx.x; c < NPAD * 49; c += 256) {
    int n = c / 49, k8 = c - n * 49;
    short8 v = {0, 0, 0, 0, 0, 0, 0, 0};
    if (k8 < 48 && n < 52) {          // k8==48 is the K-pad chunk; rows 52..63 zero
      const float* w; int lo;
      if      (n < 4)  { w = occ_w; lo = n; }
      else if (n < 16) { w = loc_w; lo = n - 4; }
      else if (n < 20) { w = ang_w; lo = n - 16; }
      else if (n < 32) { w = siz_w; lo = n - 20; }
      else if (n < 36) { w = hea_w; lo = n - 32; }
      else             { w = clf_w; lo = n - 36; }
      const f32x4* src = (const f32x4*)(w + lo * CIN + k8 * 8);
      f32x4 f0 = src[0], f1 = src[1];
      union { unsigned u[4]; short8 s; } t;
      t.u[0] = bfpk(f0.x, f0.y);
      t.u[1] = bfpk(f0.z, f0.w);
      t.u[2] = bfpk(f1.x, f1.y);
      t.u[3] = bfpk(f1.z, f1.w);
      v = t.s;
    }
    *(short8*)(Wl + (size_t)n * KPAD + k8 * 8) = v;
  }
  if (threadIdx.x < NPAD) {
    int c = threadIdx.x;
    float bv = 0.f;
    if      (c < 4)  bv = occ_b[c];
    else if (c < 16) bv = loc_b[c - 4];
    else if (c < 20) bv = ang_b[c - 16];
    else if (c < 32) bv = siz_b[c - 20];
    else if (c < 36) bv = hea_b[c - 32];
    else if (c < 52) bv = clf_b[c - 36];
    biasl[c] = bv;
  }
  __syncthreads();

  const int lane = threadIdx.x & 63;
  const int wave = threadIdx.x >> 6;
  const int m = lane & 15;        // A row / B col / C col
  const int quad = lane >> 4;     // k-group for A/B; row-group for C
  const unsigned short* wbase = Wl + (size_t)m * KPAD + quad * 8;

  int pbase[TILES_PB];
  const float* xrow[TILES_PB];
  #pragma unroll
  for (int t = 0; t < TILES_PB; ++t) {
    pbase[t] = blockIdx.x * PIX_PB + t * 64 + wave * 16;
    xrow[t] = x + (size_t)(pbase[t] + m) * CIN + quad * 8;
  }

  f32x4 acc[TILES_PB][4];
  #pragma unroll
  for (int t = 0; t < TILES_PB; ++t)
    #pragma unroll
    for (int n = 0; n < 4; ++n) acc[t][n] = (f32x4){0.f, 0.f, 0.f, 0.f};

  // K-loop: 12 steps of K=32. One set of B-fragment ds_reads feeds 3 tiles.
  #pragma unroll 2
  for (int kit = 0; kit < 12; ++kit) {
    const unsigned short* wk = wbase + kit * 32;
    short8 b0 = *(const short8*)(wk);
    short8 b1 = *(const short8*)(wk + 16 * KPAD);
    short8 b2 = *(const short8*)(wk + 32 * KPAD);
    short8 b3 = *(const short8*)(wk + 48 * KPAD);
    #pragma unroll
    for (int t = 0; t < TILES_PB; ++t) {
      const f32x4* px = (const f32x4*)(xrow[t] + kit * 32);
      f32x4 f0 = px[0];
      f32x4 f1 = px[1];
      union { unsigned u[4]; short8 s; } a;
      a.u[0] = bfpk(f0.x, f0.y);
      a.u[1] = bfpk(f0.z, f0.w);
      a.u[2] = bfpk(f1.x, f1.y);
      a.u[3] = bfpk(f1.z, f1.w);
      acc[t][0] = __builtin_amdgcn_mfma_f32_16x16x32_bf16(a.s, b0, acc[t][0], 0, 0, 0);
      acc[t][1] = __builtin_amdgcn_mfma_f32_16x16x32_bf16(a.s, b1, acc[t][1], 0, 0, 0);
      acc[t][2] = __builtin_amdgcn_mfma_f32_16x16x32_bf16(a.s, b2, acc[t][2], 0, 0, 0);
      acc[t][3] = __builtin_amdgcn_mfma_f32_16x16x32_bf16(a.s, b3, acc[t][3], 0, 0, 0);
    }
  }

  // Epilogue: C/D layout col = lane&15 (channel within n-tile),
  // row = quad*4 + reg (pixel within m-tile). Map channel c -> tensor.
  #pragma unroll
  for (int t = 0; t < TILES_PB; ++t) {
    #pragma unroll
    for (int nt = 0; nt < 4; ++nt) {
      int c = nt * 16 + m;
      if (c < 52) {
        size_t base; int stride, ch; bool sig = false;
        if      (c < 4)  { base = 0;                stride = 4;  ch = c;      sig = true; }
        else if (c < 16) { base = (size_t)PIX * 4;  stride = 12; ch = c - 4;  }
        else if (c < 20) { base = (size_t)PIX * 16; stride = 4;  ch = c - 16; }
        else if (c < 32) { base = (size_t)PIX * 20; stride = 12; ch = c - 20; }
        else if (c < 36) { base = (size_t)PIX * 32; stride = 4;  ch = c - 32; sig = true; }
        else             { base = (size_t)PIX * 36; stride = 16; ch = c - 36; }
        float bv = biasl[c];
        #pragma unroll
        for (int r = 0; r < 4; ++r) {
          int p = pbase[t] + quad * 4 + r;
          float v = acc[t][nt][r] + bv;
          if (sig) v = 1.f / (1.f + __expf(-v));
          out[base + (size_t)p * stride + ch] = v;
        }
      }
    }
  }
}

extern "C" void kernel_launch(void* const* d_in, const int* in_sizes, int n_in,
                              void* d_out, int out_size, void* d_ws, size_t ws_size,
                              hipStream_t stream) {
  const float* x     = (const float*)d_in[0];
  const float* occ_w = (const float*)d_in[1];
  const float* occ_b = (const float*)d_in[2];
  const float* loc_w = (const float*)d_in[3];
  const float* loc_b = (const float*)d_in[4];
  const float* ang_w = (const float*)d_in[5];
  const float* ang_b = (const float*)d_in[6];
  const float* siz_w = (const float*)d_in[7];
  const float* siz_b = (const float*)d_in[8];
  const float* hea_w = (const float*)d_in[9];
  const float* hea_b = (const float*)d_in[10];
  const float* clf_w = (const float*)d_in[11];
  const float* clf_b = (const float*)d_in[12];

  head_kernel<<<NBLOCKS, 256, 0, stream>>>(
      x, occ_w, occ_b, loc_w, loc_b, ang_w, ang_b, siz_w, siz_b,
      hea_w, hea_b, clf_w, clf_b, (float*)d_out);
}

// Round 3
// 548.995 us; speedup vs baseline: 1.0194x; 1.0194x over previous
//
#include <hip/hip_runtime.h>

// detection_head: six 1x1 convs over [4,252,252,384] fp32 -> 52 channels.
// Strategy: per-pixel GEMM M=254016, K=384, N=52 (padded to 64) via
// mfma_f32_16x16x32_bf16. Memory-bound (~443 MB/launch); bf16 MFMA makes
// compute negligible vs the fp32-VALU alternative.
//
// Session note (R2 post-mortem): ~478 us of the measured dur is two
// harness-enqueued 1.56 GB fillBufferAligned poisons (present even when the
// kernel never touches d_ws). prep+head = ~66 us vs ~68 us HBM roofline for
// 390 MB x-read + 53 MB out-write. Fusing weight-pack into head (R1/R2)
// regressed +15 us: per-block fp32->bf16 convert x 1323 blocks beats the
// 3 us one-time prep kernel. This two-kernel version is the optimum found.

#define HH 252
#define WW 252
#define BB 4
#define CIN 384
#define PIX (BB*HH*WW)            // 254016
#define NPAD 64
#define KPAD 392                  // 384 + 8 bf16 pad -> row stride 784 B (bank offset 4)
#define WIMG_USHORTS (NPAD*KPAD)  // 25088
#define WIMG_BYTES (WIMG_USHORTS*2)       // 50176
#define LDS_BYTES (WIMG_BYTES + NPAD*4)   // 50432

typedef __attribute__((ext_vector_type(8))) short short8;
typedef __attribute__((ext_vector_type(4))) float f32x4;
typedef __attribute__((ext_vector_type(4))) unsigned int uint4v;

__device__ __forceinline__ unsigned bfpk(float a, float b) {
  // two RNE bf16 packed into one u32 (low = a, high = b)
  unsigned ua = __float_as_uint(a), ub = __float_as_uint(b);
  ua = (ua + 0x7FFFu + ((ua >> 16) & 1u)) >> 16;
  ub = (ub + 0x7FFFu + ((ub >> 16) & 1u)) >> 16;
  return ua | (ub << 16);
}
__device__ __forceinline__ unsigned short f2bf(float a) {
  unsigned ua = __float_as_uint(a);
  return (unsigned short)((ua + 0x7FFFu + ((ua >> 16) & 1u)) >> 16);
}

// Pack the 6 weight matrices into bf16 image [64][KPAD] (rows 52..63 and
// cols 384..391 zero) + 64 fp32 biases. Runs every launch (ws is re-poisoned).
__global__ void prep_kernel(
    const float* __restrict__ occ_w, const float* __restrict__ occ_b,
    const float* __restrict__ loc_w, const float* __restrict__ loc_b,
    const float* __restrict__ ang_w, const float* __restrict__ ang_b,
    const float* __restrict__ siz_w, const float* __restrict__ siz_b,
    const float* __restrict__ hea_w, const float* __restrict__ hea_b,
    const float* __restrict__ clf_w, const float* __restrict__ clf_b,
    unsigned short* __restrict__ wimg, float* __restrict__ bimg) {
  int idx = blockIdx.x * 256 + threadIdx.x;
  if (idx < WIMG_USHORTS) {
    int n = idx / KPAD, k = idx % KPAD;
    float v = 0.f;
    if (k < CIN) {
      const float* w = nullptr; int lo = 0;
      if      (n < 4)  { w = occ_w; lo = n; }
      else if (n < 16) { w = loc_w; lo = n - 4; }
      else if (n < 20) { w = ang_w; lo = n - 16; }
      else if (n < 32) { w = siz_w; lo = n - 20; }
      else if (n < 36) { w = hea_w; lo = n - 32; }
      else if (n < 52) { w = clf_w; lo = n - 36; }
      if (w) v = w[lo * CIN + k];
    }
    wimg[idx] = f2bf(v);
  } else if (idx < WIMG_USHORTS + NPAD) {
    int c = idx - WIMG_USHORTS;
    float v = 0.f;
    if      (c < 4)  v = occ_b[c];
    else if (c < 16) v = loc_b[c - 4];
    else if (c < 20) v = ang_b[c - 16];
    else if (c < 32) v = siz_b[c - 20];
    else if (c < 36) v = hea_b[c - 32];
    else if (c < 52) v = clf_b[c - 36];
    bimg[c] = v;
  }
}

// Block = 256 threads = 4 waves; 64 pixels/block (wave handles M=16 x N=64).
// Weights staged to LDS once; K-loop has no barriers.
__global__ __launch_bounds__(256, 3) void head_kernel(
    const float* __restrict__ x, const uint4v* __restrict__ wsimg,
    float* __restrict__ out) {
  __shared__ __align__(16) unsigned char lds_raw[LDS_BYTES];
  {
    uint4v* dst = (uint4v*)lds_raw;
    for (int u = threadIdx.x; u < LDS_BYTES / 16; u += 256) dst[u] = wsimg[u];
  }
  __syncthreads();
  const unsigned short* Wl = (const unsigned short*)lds_raw;
  const float* biasl = (const float*)(lds_raw + WIMG_BYTES);

  const int lane = threadIdx.x & 63;
  const int wave = threadIdx.x >> 6;
  const int m = lane & 15;        // A row / B col / C col
  const int quad = lane >> 4;     // k-group for A/B; row-group for C
  const int pixel_base = blockIdx.x * 64 + wave * 16;
  const float* xrow = x + (size_t)(pixel_base + m) * CIN + quad * 8;

  f32x4 acc0 = {0.f, 0.f, 0.f, 0.f};
  f32x4 acc1 = {0.f, 0.f, 0.f, 0.f};
  f32x4 acc2 = {0.f, 0.f, 0.f, 0.f};
  f32x4 acc3 = {0.f, 0.f, 0.f, 0.f};

  const unsigned short* wbase = Wl + (size_t)m * KPAD + quad * 8;

  #pragma unroll 4
  for (int kit = 0; kit < 12; ++kit) {
    const f32x4* px = (const f32x4*)(xrow + kit * 32);
    f32x4 f0 = px[0];
    f32x4 f1 = px[1];
    union { unsigned u[4]; short8 s; } a;
    a.u[0] = bfpk(f0.x, f0.y);
    a.u[1] = bfpk(f0.z, f0.w);
    a.u[2] = bfpk(f1.x, f1.y);
    a.u[3] = bfpk(f1.z, f1.w);
    const unsigned short* wk = wbase + kit * 32;
    short8 b0 = *(const short8*)(wk);
    short8 b1 = *(const short8*)(wk + 16 * KPAD);
    short8 b2 = *(const short8*)(wk + 32 * KPAD);
    short8 b3 = *(const short8*)(wk + 48 * KPAD);
    acc0 = __builtin_amdgcn_mfma_f32_16x16x32_bf16(a.s, b0, acc0, 0, 0, 0);
    acc1 = __builtin_amdgcn_mfma_f32_16x16x32_bf16(a.s, b1, acc1, 0, 0, 0);
    acc2 = __builtin_amdgcn_mfma_f32_16x16x32_bf16(a.s, b2, acc2, 0, 0, 0);
    acc3 = __builtin_amdgcn_mfma_f32_16x16x32_bf16(a.s, b3, acc3, 0, 0, 0);
  }

  // Epilogue: C/D layout col = lane&15 (channel within n-tile),
  // row = quad*4 + reg (pixel within m-tile). Map channel c -> tensor.
  f32x4 accs[4] = {acc0, acc1, acc2, acc3};
  #pragma unroll
  for (int nt = 0; nt < 4; ++nt) {
    int c = nt * 16 + m;
    if (c < 52) {
      size_t base; int stride, ch; bool sig = false;
      if      (c < 4)  { base = 0;                stride = 4;  ch = c;      sig = true; }
      else if (c < 16) { base = (size_t)PIX * 4;  stride = 12; ch = c - 4;  }
      else if (c < 20) { base = (size_t)PIX * 16; stride = 4;  ch = c - 16; }
      else if (c < 32) { base = (size_t)PIX * 20; stride = 12; ch = c - 20; }
      else if (c < 36) { base = (size_t)PIX * 32; stride = 4;  ch = c - 32; sig = true; }
      else             { base = (size_t)PIX * 36; stride = 16; ch = c - 36; }
      float bv = biasl[c];
      #pragma unroll
      for (int r = 0; r < 4; ++r) {
        int p = pixel_base + quad * 4 + r;
        float v = accs[nt][r] + bv;
        if (sig) v = 1.f / (1.f + __expf(-v));
        out[base + (size_t)p * stride + ch] = v;
      }
    }
  }
}

extern "C" void kernel_launch(void* const* d_in, const int* in_sizes, int n_in,
                              void* d_out, int out_size, void* d_ws, size_t ws_size,
                              hipStream_t stream) {
  const float* x     = (const float*)d_in[0];
  const float* occ_w = (const float*)d_in[1];
  const float* occ_b = (const float*)d_in[2];
  const float* loc_w = (const float*)d_in[3];
  const float* loc_b = (const float*)d_in[4];
  const float* ang_w = (const float*)d_in[5];
  const float* ang_b = (const float*)d_in[6];
  const float* siz_w = (const float*)d_in[7];
  const float* siz_b = (const float*)d_in[8];
  const float* hea_w = (const float*)d_in[9];
  const float* hea_b = (const float*)d_in[10];
  const float* clf_w = (const float*)d_in[11];
  const float* clf_b = (const float*)d_in[12];

  unsigned short* wimg = (unsigned short*)d_ws;
  float* bimg = (float*)((char*)d_ws + WIMG_BYTES);

  prep_kernel<<<(WIMG_USHORTS + NPAD + 255) / 256, 256, 0, stream>>>(
      occ_w, occ_b, loc_w, loc_b, ang_w, ang_b, siz_w, siz_b, hea_w, hea_b,
      clf_w, clf_b, wimg, bimg);

  head_kernel<<<PIX / 64, 256, 0, stream>>>(x, (const uint4v*)d_ws,
                                            (float*)d_out);
}